// Round 1
// baseline (141.621 us; speedup 1.0000x reference)
//
#include <hip/hip_runtime.h>

typedef unsigned short ushort_t;
typedef unsigned int uint_t;

typedef __bf16 bf16x8 __attribute__((ext_vector_type(8)));
typedef float f32x4 __attribute__((ext_vector_type(4)));

#define KK 588       // true K
#define KP 608       // padded K (19 * 32)
#define NN 1152      // N (output cols)
#define MM 32768     // M (output rows)
#define POSROWS 4096 // h*w per image

// ---------------- helpers ----------------

__device__ __forceinline__ ushort_t f2bf(float f) {
    union { float f; uint_t u; } v; v.f = f;
    uint_t u = v.u;
    uint_t r = (u + 0x7FFFu + ((u >> 16) & 1u)) >> 16; // round-nearest-even
    return (ushort_t)r;
}

__device__ __forceinline__ void cubic_taps(int dst, float* w, int* idx) {
    const float A = -0.75f;
    float src = (float)dst * 0.25f - 0.25f;   // (dst+0.5)*16/64 - 0.5
    int x0 = (int)floorf(src);
    #pragma unroll
    for (int k = -1; k <= 2; ++k) {
        int i = x0 + k;
        int ic = i < 0 ? 0 : (i > 15 ? 15 : i);
        float d = fabsf(src - (float)i);
        float wt;
        if (d <= 1.0f)      wt = ((A + 2.0f) * d - (A + 3.0f)) * d * d + 1.0f;
        else if (d < 2.0f)  wt = ((A * d - 5.0f * A) * d + 8.0f * A) * d - 4.0f * A;
        else                wt = 0.0f;
        w[k + 1] = wt;
        idx[k + 1] = ic;
    }
}

// ---------------- pos embedding: (4096, 1152) fp32 into ws ----------------

__global__ void pos_kernel(const float* __restrict__ pt, float* __restrict__ pos) {
    int n = blockIdx.x; // 0..4095 (rearranged row)
    // inverse of the hidden_stride=2 rearrange
    int h = ((n >> 7) << 1) | ((n >> 1) & 1);
    int w = (((n >> 2) & 31) << 1) | (n & 1);
    float wh[4], ww[4];
    int ih[4], iw[4];
    cubic_taps(h, wh, ih);
    cubic_taps(w, ww, iw);
    for (int j = threadIdx.x; j < NN; j += blockDim.x) {
        float s = 0.f;
        #pragma unroll
        for (int a = 0; a < 4; ++a) {
            float rs = 0.f;
            #pragma unroll
            for (int b = 0; b < 4; ++b)
                rs += ww[b] * pt[(ih[a] * 16 + iw[b]) * NN + j];
            s += wh[a] * rs;
        }
        pos[(size_t)n * NN + j] = s;
    }
}

// ---------------- f32 -> bf16 with K padding 588 -> 608 ----------------

__global__ void cvt_pad_kernel(const float* __restrict__ src, ushort_t* __restrict__ dst,
                               int rows) {
    int idx = blockIdx.x * 256 + threadIdx.x;
    int total = rows * KP;
    if (idx >= total) return;
    int row = idx / KP;
    int k = idx - row * KP;
    float v = (k < KK) ? src[(size_t)row * KK + k] : 0.0f;
    dst[idx] = f2bf(v);
}

// ---------------- bf16 MFMA GEMM + bias + pos epilogue ----------------
// A: [MM][KP] bf16 (pixel values), B: [NN][KP] bf16 (w_patch rows = out cols)
// out[m][n] = sum_k A[m][k]*B[n][k] + bias[n] + pos[m & 4095][n]

__global__ void gemm_kernel(const ushort_t* __restrict__ Abf,
                            const ushort_t* __restrict__ Bbf,
                            const float* __restrict__ bias,
                            const float* __restrict__ pos,
                            float* __restrict__ out) {
    __shared__ __align__(16) ushort_t lA[128 * 32]; // [row][32k], 16B slots swizzled
    __shared__ __align__(16) ushort_t lB[128 * 32];

    const int t = threadIdx.x;
    const int lane = t & 63;
    const int wid = t >> 6;
    const int wm = wid >> 1, wn = wid & 1;

    const int bm = (int)blockIdx.x * 128;
    const int bn = (int)blockIdx.y * 128;

    f32x4 acc[4][4] = {};

    for (int ks = 0; ks < KP / 32; ++ks) {
        const int k0 = ks * 32;
        // stage A and B tiles via global_load_lds (16B/lane), source pre-swizzled
        #pragma unroll
        for (int i = 0; i < 2; ++i) {
            int idx = i * 256 + t;
            int row = idx >> 2;
            int slot = idx & 3;
            int khi = slot ^ ((row >> 1) & 3); // inverse swizzle on source
            const ushort_t* gA = Abf + (size_t)(bm + row) * KP + k0 + khi * 8;
            const ushort_t* gB = Bbf + (size_t)(bn + row) * KP + k0 + khi * 8;
            ushort_t* lAp = lA + (size_t)(idx & ~63) * 8; // wave-uniform base (16B/lane)
            ushort_t* lBp = lB + (size_t)(idx & ~63) * 8;
            __builtin_amdgcn_global_load_lds(
                (const __attribute__((address_space(1))) void*)gA,
                (__attribute__((address_space(3))) void*)lAp, 16, 0, 0);
            __builtin_amdgcn_global_load_lds(
                (const __attribute__((address_space(1))) void*)gB,
                (__attribute__((address_space(3))) void*)lBp, 16, 0, 0);
        }
        __syncthreads();

        bf16x8 af[4], bfr[4];
        #pragma unroll
        for (int mi = 0; mi < 4; ++mi) {
            int row = wm * 64 + mi * 16 + (lane & 15);
            int slot = (lane >> 4) ^ ((row >> 1) & 3); // swizzled read
            af[mi] = *(const bf16x8*)(lA + row * 32 + slot * 8);
        }
        #pragma unroll
        for (int ni = 0; ni < 4; ++ni) {
            int row = wn * 64 + ni * 16 + (lane & 15);
            int slot = (lane >> 4) ^ ((row >> 1) & 3);
            bfr[ni] = *(const bf16x8*)(lB + row * 32 + slot * 8);
        }
        #pragma unroll
        for (int mi = 0; mi < 4; ++mi)
            #pragma unroll
            for (int ni = 0; ni < 4; ++ni)
                acc[mi][ni] = __builtin_amdgcn_mfma_f32_16x16x32_bf16(
                    af[mi], bfr[ni], acc[mi][ni], 0, 0, 0);
        __syncthreads();
    }

    // epilogue: C/D layout col = lane&15, row = (lane>>4)*4 + r
    #pragma unroll
    for (int mi = 0; mi < 4; ++mi) {
        #pragma unroll
        for (int ni = 0; ni < 4; ++ni) {
            int col = bn + wn * 64 + ni * 16 + (lane & 15);
            float bcol = bias[col];
            #pragma unroll
            for (int r = 0; r < 4; ++r) {
                int row = bm + wm * 64 + mi * 16 + (lane >> 4) * 4 + r;
                int prow = row & (POSROWS - 1);
                out[(size_t)row * NN + col] =
                    acc[mi][ni][r] + bcol + pos[(size_t)prow * NN + col];
            }
        }
    }
}

// ---------------- fallback (ws too small): naive fp32 ----------------

__global__ void fb_kernel(const float* __restrict__ A, const float* __restrict__ W,
                          const float* __restrict__ bias, const float* __restrict__ pt,
                          float* __restrict__ out) {
    __shared__ float sA[16][17], sB[16][17];
    int ty = threadIdx.y, tx = threadIdx.x;
    int row = blockIdx.y * 16 + ty; // M
    int col = blockIdx.x * 16 + tx; // N
    float acc = 0.f;
    for (int k0 = 0; k0 < KK; k0 += 16) {
        int ka = k0 + tx;
        sA[ty][tx] = (ka < KK) ? A[(size_t)row * KK + ka] : 0.f;
        sB[ty][tx] = (ka < KK) ? W[(size_t)(blockIdx.x * 16 + ty) * KK + ka] : 0.f;
        __syncthreads();
        #pragma unroll
        for (int kk = 0; kk < 16; ++kk)
            acc += sA[ty][kk] * sB[tx][kk];
        __syncthreads();
    }
    int n = row & (POSROWS - 1);
    int h = ((n >> 7) << 1) | ((n >> 1) & 1);
    int w = (((n >> 2) & 31) << 1) | (n & 1);
    float wh[4], ww[4]; int ih[4], iw[4];
    cubic_taps(h, wh, ih);
    cubic_taps(w, ww, iw);
    float p = 0.f;
    #pragma unroll
    for (int a = 0; a < 4; ++a) {
        float rs = 0.f;
        #pragma unroll
        for (int b = 0; b < 4; ++b)
            rs += ww[b] * pt[(ih[a] * 16 + iw[b]) * NN + col];
        p += wh[a] * rs;
    }
    out[(size_t)row * NN + col] = acc + bias[col] + p;
}

// ---------------- launch ----------------

extern "C" void kernel_launch(void* const* d_in, const int* in_sizes, int n_in,
                              void* d_out, int out_size, void* d_ws, size_t ws_size,
                              hipStream_t stream) {
    const float* pv   = (const float*)d_in[0]; // (32768, 588)
    const float* wp   = (const float*)d_in[1]; // (1152, 588)
    const float* bias = (const float*)d_in[2]; // (1152,)
    const float* pt   = (const float*)d_in[3]; // (256, 1152)
    float* out = (float*)d_out;

    const size_t pos_bytes = (size_t)POSROWS * NN * 4;   // 18,874,368
    const size_t pvb_bytes = (size_t)MM * KP * 2;        // 39,845,888
    const size_t wb_bytes  = (size_t)NN * KP * 2;        //  1,400,832
    const size_t need = pos_bytes + pvb_bytes + wb_bytes;

    if (ws_size >= need) {
        float* pos = (float*)d_ws;
        ushort_t* pvb = (ushort_t*)((char*)d_ws + pos_bytes);
        ushort_t* wb  = (ushort_t*)((char*)d_ws + pos_bytes + pvb_bytes);

        pos_kernel<<<POSROWS, 256, 0, stream>>>(pt, pos);

        int tot_pv = MM * KP;
        cvt_pad_kernel<<<(tot_pv + 255) / 256, 256, 0, stream>>>(pv, pvb, MM);
        int tot_w = NN * KP;
        cvt_pad_kernel<<<(tot_w + 255) / 256, 256, 0, stream>>>(wp, wb, NN);

        gemm_kernel<<<dim3(MM / 128, NN / 128), 256, 0, stream>>>(pvb, wb, bias, pos, out);
    } else {
        fb_kernel<<<dim3(NN / 16, MM / 16), dim3(16, 16), 0, stream>>>(pv, wp, bias, pt, out);
    }
}